// Round 5
// baseline (773.908 us; speedup 1.0000x reference)
//
#include <hip/hip_runtime.h>
#include <hip/hip_cooperative_groups.h>

namespace cg = cooperative_groups;

// PillarFeatureNet scatter-sum:
//   out[c, p] = sum_{i : indices[i]==p} x[i, c]
// x: (2,000,000, 64) fp32, indices: (2,000,000) int32 in [0, 262144)
// out: (64, 262144) fp32
//
// Round 5: single cooperative kernel (zero -> hist -> scan -> scatter ->
// gather with grid.sync() between phases). R4 showed top-5 rocprof rows all
// harness-side 2GB fills (~290us) -- fusing gives one visible dispatch row
// for our whole pipeline and removes 4 launch gaps. Gather gets unroll-2
// dual accumulators (2 HBM loads in flight per lane).
//
// ws layout: [counts: NB i32][gtotal+pad: 64 i32][cursors: NB i32]
//            [sorted: NP i32]   total ~10.1 MB

#define NP   2000000
#define NB   262144          // 512*512 pillars
#define NBLK 1024
#define NTHR 256
#define NALL (NBLK * NTHR)   // 262144 threads == NB (1 bin per thread in scan)

__global__ __launch_bounds__(NTHR, 4) void pillar_fused_kernel(
    const float4* __restrict__ x4,
    const int4*   __restrict__ idx4,
    int*          __restrict__ counts,    // [NB]
    int*          __restrict__ gtotal,    // [1]
    int*          __restrict__ cursors,   // [NB]
    int*          __restrict__ sorted,    // [NP]
    float*        __restrict__ out)       // [64 * NB]
{
    cg::grid_group grid = cg::this_grid();
    __shared__ float tile[64][65];        // gather transpose tile (16.6 KB)
    __shared__ int blockBase;
    const int tid  = threadIdx.x;
    const int gtid = blockIdx.x * NTHR + tid;

    // ---- Phase 0: zero counts + gtotal (ws is poisoned 0xAA) ----
    counts[gtid] = 0;                     // NALL == NB
    if (gtid == 0) *gtotal = 0;
    grid.sync();

    // ---- Phase 1: histogram (2M int atomics on 1 MB counts) ----
    for (int i = gtid; i < NP / 4; i += NALL) {
        const int4 v = idx4[i];
        atomicAdd(&counts[v.x], 1);
        atomicAdd(&counts[v.y], 1);
        atomicAdd(&counts[v.z], 1);
        atomicAdd(&counts[v.w], 1);
    }
    grid.sync();

    // ---- Phase 2: exclusive scan, 1 bin/thread. Block-local Hillis-Steele
    //      + atomic ticket for block base (bin order across blocks is
    //      irrelevant: any disjoint partition of [0,NP) is a valid CSR). ----
    {
        int* lsum = reinterpret_cast<int*>(&tile[0][0]);
        const int c = counts[gtid];
        lsum[tid] = c;
        __syncthreads();
        #pragma unroll
        for (int off = 1; off < NTHR; off <<= 1) {
            const int v = (tid >= off) ? lsum[tid - off] : 0;
            __syncthreads();
            lsum[tid] += v;
            __syncthreads();
        }
        const int incl = lsum[tid];
        if (tid == NTHR - 1) blockBase = atomicAdd(gtotal, incl);
        __syncthreads();
        cursors[gtid] = blockBase + incl - c;   // exclusive start of bin gtid
    }
    grid.sync();

    // ---- Phase 3: scatter point ids into pillar-sorted order ----
    for (int i = gtid; i < NP / 4; i += NALL) {
        const int4 v = idx4[i];
        const int base = 4 * i;
        int pos;
        pos = atomicAdd(&cursors[v.x], 1); sorted[pos] = base + 0;
        pos = atomicAdd(&cursors[v.y], 1); sorted[pos] = base + 1;
        pos = atomicAdd(&cursors[v.z], 1); sorted[pos] = base + 2;
        pos = atomicAdd(&cursors[v.w], 1); sorted[pos] = base + 3;
    }
    grid.sync();

    // ---- Phase 4: gather-sum + LDS transpose. 4 tiles of 64 pillars per
    //      block; 16 lanes per pillar (lane j owns channels 4j..4j+3). ----
    const int j = tid & 15;
    const int g = tid >> 4;
    for (int k2 = 0; k2 < 4; ++k2) {
        __syncthreads();                  // tile reuse barrier
        const int p0 = (blockIdx.x * 4 + k2) * 64;
        #pragma unroll
        for (int k = 0; k < 4; ++k) {
            const int pl  = g + 16 * k;
            const int p   = p0 + pl;
            const int end = cursors[p];   // post-scatter cursor == segment end
            const int cnt = counts[p];
            float4 a0 = make_float4(0.f, 0.f, 0.f, 0.f);
            float4 a1 = make_float4(0.f, 0.f, 0.f, 0.f);
            int t = end - cnt;
            for (; t + 1 < end; t += 2) {          // 2 loads in flight
                const int i0 = sorted[t];
                const int i1 = sorted[t + 1];
                const float4 v0 = x4[(size_t)i0 * 16 + j];
                const float4 v1 = x4[(size_t)i1 * 16 + j];
                a0.x += v0.x; a0.y += v0.y; a0.z += v0.z; a0.w += v0.w;
                a1.x += v1.x; a1.y += v1.y; a1.z += v1.z; a1.w += v1.w;
            }
            if (t < end) {
                const int i0 = sorted[t];
                const float4 v0 = x4[(size_t)i0 * 16 + j];
                a0.x += v0.x; a0.y += v0.y; a0.z += v0.z; a0.w += v0.w;
            }
            tile[4 * j + 0][pl] = a0.x + a1.x;
            tile[4 * j + 1][pl] = a0.y + a1.y;
            tile[4 * j + 2][pl] = a0.z + a1.z;
            tile[4 * j + 3][pl] = a0.w + a1.w;
        }
        __syncthreads();
        const int pl = tid & 63;
        const int cb = tid >> 6;
        #pragma unroll
        for (int c4 = 0; c4 < 64; c4 += 4) {
            const int c = c4 + cb;
            out[(size_t)c * NB + p0 + pl] = tile[c][pl];
        }
    }
}

// ======== Fallback: R4 multi-kernel path (if cooperative launch fails) ======

__global__ __launch_bounds__(256) void zero_kernel(int* __restrict__ p, int n)
{
    const int stride = gridDim.x * blockDim.x;
    for (int i = blockIdx.x * blockDim.x + threadIdx.x; i < n; i += stride)
        p[i] = 0;
}

__global__ __launch_bounds__(256) void hist_kernel(
    const int4* __restrict__ idx4, int* __restrict__ counts)
{
    const int stride = gridDim.x * blockDim.x;
    for (int i = blockIdx.x * blockDim.x + threadIdx.x; i < NP / 4; i += stride) {
        const int4 v = idx4[i];
        atomicAdd(&counts[v.x], 1);
        atomicAdd(&counts[v.y], 1);
        atomicAdd(&counts[v.z], 1);
        atomicAdd(&counts[v.w], 1);
    }
}

__global__ __launch_bounds__(256) void scan_kernel(
    const int4* __restrict__ counts4, int* __restrict__ gtotal,
    int4* __restrict__ cursors4)
{
    __shared__ int lsum[256];
    __shared__ int blockBase;
    const int tid = threadIdx.x;
    const int gidx = blockIdx.x * 256 + tid;
    const int4 c = counts4[gidx];
    const int s = c.x + c.y + c.z + c.w;
    lsum[tid] = s;
    __syncthreads();
    #pragma unroll
    for (int off = 1; off < 256; off <<= 1) {
        const int v = (tid >= off) ? lsum[tid - off] : 0;
        __syncthreads();
        lsum[tid] += v;
        __syncthreads();
    }
    const int incl = lsum[tid];
    if (tid == 255) blockBase = atomicAdd(gtotal, incl);
    __syncthreads();
    const int e = blockBase + (incl - s);
    cursors4[gidx] = make_int4(e, e + c.x, e + c.x + c.y, e + c.x + c.y + c.z);
}

__global__ __launch_bounds__(256) void scatter_kernel(
    const int4* __restrict__ idx4, int* __restrict__ cursors,
    int* __restrict__ sorted)
{
    const int stride = gridDim.x * blockDim.x;
    for (int i = blockIdx.x * blockDim.x + threadIdx.x; i < NP / 4; i += stride) {
        const int4 v = idx4[i];
        const int base = 4 * i;
        int pos;
        pos = atomicAdd(&cursors[v.x], 1); sorted[pos] = base + 0;
        pos = atomicAdd(&cursors[v.y], 1); sorted[pos] = base + 1;
        pos = atomicAdd(&cursors[v.z], 1); sorted[pos] = base + 2;
        pos = atomicAdd(&cursors[v.w], 1); sorted[pos] = base + 3;
    }
}

__global__ __launch_bounds__(256) void gather_kernel(
    const float4* __restrict__ x4,
    const int*    __restrict__ counts,
    const int*    __restrict__ ends,
    const int*    __restrict__ sorted,
    float*        __restrict__ out)
{
    __shared__ float tile[64][65];
    const int p0 = blockIdx.x * 64;
    const int j  = threadIdx.x & 15;
    const int g  = threadIdx.x >> 4;
    #pragma unroll
    for (int k = 0; k < 4; ++k) {
        const int pl  = g + 16 * k;
        const int p   = p0 + pl;
        const int end = ends[p];
        const int cnt = counts[p];
        float4 a0 = make_float4(0.f, 0.f, 0.f, 0.f);
        float4 a1 = make_float4(0.f, 0.f, 0.f, 0.f);
        int t = end - cnt;
        for (; t + 1 < end; t += 2) {
            const int i0 = sorted[t];
            const int i1 = sorted[t + 1];
            const float4 v0 = x4[(size_t)i0 * 16 + j];
            const float4 v1 = x4[(size_t)i1 * 16 + j];
            a0.x += v0.x; a0.y += v0.y; a0.z += v0.z; a0.w += v0.w;
            a1.x += v1.x; a1.y += v1.y; a1.z += v1.z; a1.w += v1.w;
        }
        if (t < end) {
            const int i0 = sorted[t];
            const float4 v0 = x4[(size_t)i0 * 16 + j];
            a0.x += v0.x; a0.y += v0.y; a0.z += v0.z; a0.w += v0.w;
        }
        tile[4 * j + 0][pl] = a0.x + a1.x;
        tile[4 * j + 1][pl] = a0.y + a1.y;
        tile[4 * j + 2][pl] = a0.z + a1.z;
        tile[4 * j + 3][pl] = a0.w + a1.w;
    }
    __syncthreads();
    const int pl = threadIdx.x & 63;
    const int cb = threadIdx.x >> 6;
    #pragma unroll
    for (int c4 = 0; c4 < 64; c4 += 4) {
        const int c = c4 + cb;
        out[(size_t)c * NB + p0 + pl] = tile[c][pl];
    }
}

extern "C" void kernel_launch(void* const* d_in, const int* in_sizes, int n_in,
                              void* d_out, int out_size, void* d_ws, size_t ws_size,
                              hipStream_t stream)
{
    const float4* x4   = reinterpret_cast<const float4*>(d_in[0]);
    const int4*   idx4 = reinterpret_cast<const int4*>(d_in[1]);
    float*        out  = reinterpret_cast<float*>(d_out);

    int* counts  = reinterpret_cast<int*>(d_ws);
    int* gtotal  = counts + NB;
    int* cursors = counts + NB + 64;
    int* sorted  = cursors + NB;

    void* args[] = { (void*)&x4, (void*)&idx4, (void*)&counts, (void*)&gtotal,
                     (void*)&cursors, (void*)&sorted, (void*)&out };
    hipError_t err = hipLaunchCooperativeKernel(
        (const void*)pillar_fused_kernel, dim3(NBLK), dim3(NTHR),
        args, 0, stream);
    if (err == hipSuccess) return;

    // Cooperative launch unavailable -> R4 multi-kernel path.
    zero_kernel<<<256, 256, 0, stream>>>(counts, NB + 64);
    hist_kernel<<<2048, 256, 0, stream>>>(idx4, counts);
    scan_kernel<<<NB / 1024, 256, 0, stream>>>(
        reinterpret_cast<const int4*>(counts), gtotal,
        reinterpret_cast<int4*>(cursors));
    scatter_kernel<<<2048, 256, 0, stream>>>(idx4, cursors, sorted);
    gather_kernel<<<NB / 64, 256, 0, stream>>>(x4, counts, cursors, sorted, out);
}

// Round 6
// 380.531 us; speedup vs baseline: 2.0338x; 2.0338x over previous
//
#include <hip/hip_runtime.h>

// PillarFeatureNet scatter-sum:
//   out[c, p] = sum_{i : indices[i]==p} x[i, c]
// x: (2,000,000, 64) fp32, indices: (2,000,000) int32 in [0, 262144)
// out: (64, 262144) fp32
//
// Round 6: split pipeline (R4 structure, 407us) + two fixes:
//  - scatter writes `sorted` via atomicExch: executes at the memory-side
//    coherent point, avoiding cross-XCD dirty-line bounce (R5 counters:
//    WRITE_SIZE 261MB vs ~72MB expected -> ~250MB parasitic RMW traffic).
//  - gather unroll-4 (4 dependent load chains in flight) + nontemporal
//    output stores (out has no reuse; keep cache for x).
// R5 lesson: cooperative fusion = 808us (occupancy capped at 4 blk/CU,
// grid-wide phase barriers) -- split kernels win.
//
// ws layout: [counts: NB i32][gtotal+pad: 64 i32][cursors: NB i32]
//            [sorted: NP i32]   total ~10.1 MB

#define NP   2000000
#define NB   262144          // 512*512 pillars

__global__ __launch_bounds__(256) void zero_kernel(int4* __restrict__ p, int n4)
{
    const int stride = gridDim.x * blockDim.x;
    for (int i = blockIdx.x * blockDim.x + threadIdx.x; i < n4; i += stride)
        p[i] = make_int4(0, 0, 0, 0);
}

__global__ __launch_bounds__(256) void hist_kernel(
    const int4* __restrict__ idx4, int* __restrict__ counts)
{
    const int stride = gridDim.x * blockDim.x;
    for (int i = blockIdx.x * blockDim.x + threadIdx.x; i < NP / 4; i += stride) {
        const int4 v = idx4[i];
        atomicAdd(&counts[v.x], 1);
        atomicAdd(&counts[v.y], 1);
        atomicAdd(&counts[v.z], 1);
        atomicAdd(&counts[v.w], 1);
    }
}

// 256 blocks x 256 threads, 4 bins/thread. Block base via atomic ticket:
// any disjoint partition of [0,NP) is a valid CSR (order irrelevant).
__global__ __launch_bounds__(256) void scan_kernel(
    const int4* __restrict__ counts4, int* __restrict__ gtotal,
    int4* __restrict__ cursors4)
{
    __shared__ int lsum[256];
    __shared__ int blockBase;
    const int tid = threadIdx.x;
    const int g   = blockIdx.x * 256 + tid;

    const int4 c = counts4[g];
    const int s = c.x + c.y + c.z + c.w;
    lsum[tid] = s;
    __syncthreads();
    #pragma unroll
    for (int off = 1; off < 256; off <<= 1) {
        const int v = (tid >= off) ? lsum[tid - off] : 0;
        __syncthreads();
        lsum[tid] += v;
        __syncthreads();
    }
    const int incl = lsum[tid];
    if (tid == 255) blockBase = atomicAdd(gtotal, incl);
    __syncthreads();

    const int e = blockBase + (incl - s);
    cursors4[g] = make_int4(e, e + c.x, e + c.x + c.y, e + c.x + c.y + c.z);
}

__global__ __launch_bounds__(256) void scatter_kernel(
    const int4* __restrict__ idx4, int* __restrict__ cursors,
    int* __restrict__ sorted)
{
    const int stride = gridDim.x * blockDim.x;
    for (int i = blockIdx.x * blockDim.x + threadIdx.x; i < NP / 4; i += stride) {
        const int4 v = idx4[i];
        const int base = 4 * i;
        int pos;
        // atomicExch: memory-side store, no L2 write-allocate / cross-XCD
        // dirty-line bounce (plain 4B stores cost ~130B of line traffic each).
        pos = atomicAdd(&cursors[v.x], 1); atomicExch(&sorted[pos], base + 0);
        pos = atomicAdd(&cursors[v.y], 1); atomicExch(&sorted[pos], base + 1);
        pos = atomicAdd(&cursors[v.z], 1); atomicExch(&sorted[pos], base + 2);
        pos = atomicAdd(&cursors[v.w], 1); atomicExch(&sorted[pos], base + 3);
    }
}

// One block per 64 consecutive pillars. 16 lanes per pillar (lane j owns
// channels 4j..4j+3, float4 row gathers = 256B bursts). Unroll-4 keeps 4
// dependent sorted->x chains in flight. Transpose via padded LDS tile,
// nontemporal coalesced output stores.
__global__ __launch_bounds__(256) void gather_kernel(
    const float4* __restrict__ x4,
    const int*    __restrict__ counts,
    const int*    __restrict__ ends,     // cursors after scatter = segment ends
    const int*    __restrict__ sorted,
    float*        __restrict__ out)
{
    __shared__ float tile[64][65];
    const int p0 = blockIdx.x * 64;
    const int j  = threadIdx.x & 15;
    const int g  = threadIdx.x >> 4;

    #pragma unroll
    for (int k = 0; k < 4; ++k) {
        const int pl  = g + 16 * k;
        const int p   = p0 + pl;
        const int end = ends[p];
        const int cnt = counts[p];
        float4 a0 = make_float4(0.f, 0.f, 0.f, 0.f);
        float4 a1 = a0, a2 = a0, a3 = a0;
        int t = end - cnt;
        for (; t + 3 < end; t += 4) {
            const int i0 = sorted[t + 0];
            const int i1 = sorted[t + 1];
            const int i2 = sorted[t + 2];
            const int i3 = sorted[t + 3];
            const float4 v0 = x4[(size_t)i0 * 16 + j];
            const float4 v1 = x4[(size_t)i1 * 16 + j];
            const float4 v2 = x4[(size_t)i2 * 16 + j];
            const float4 v3 = x4[(size_t)i3 * 16 + j];
            a0.x += v0.x; a0.y += v0.y; a0.z += v0.z; a0.w += v0.w;
            a1.x += v1.x; a1.y += v1.y; a1.z += v1.z; a1.w += v1.w;
            a2.x += v2.x; a2.y += v2.y; a2.z += v2.z; a2.w += v2.w;
            a3.x += v3.x; a3.y += v3.y; a3.z += v3.z; a3.w += v3.w;
        }
        for (; t < end; ++t) {
            const int i0 = sorted[t];
            const float4 v0 = x4[(size_t)i0 * 16 + j];
            a0.x += v0.x; a0.y += v0.y; a0.z += v0.z; a0.w += v0.w;
        }
        tile[4 * j + 0][pl] = a0.x + a1.x + a2.x + a3.x;
        tile[4 * j + 1][pl] = a0.y + a1.y + a2.y + a3.y;
        tile[4 * j + 2][pl] = a0.z + a1.z + a2.z + a3.z;
        tile[4 * j + 3][pl] = a0.w + a1.w + a2.w + a3.w;
    }
    __syncthreads();

    const int pl = threadIdx.x & 63;
    const int cb = threadIdx.x >> 6;
    #pragma unroll
    for (int c4 = 0; c4 < 64; c4 += 4) {
        const int c = c4 + cb;
        __builtin_nontemporal_store(tile[c][pl], &out[(size_t)c * NB + p0 + pl]);
    }
}

// ---- Fallback (direct-atomic path) if workspace is too small ----
__global__ __launch_bounds__(256) void zero_out_kernel(float4* __restrict__ p, int n4)
{
    const int stride = gridDim.x * blockDim.x;
    for (int i = blockIdx.x * blockDim.x + threadIdx.x; i < n4; i += stride)
        p[i] = make_float4(0.f, 0.f, 0.f, 0.f);
}

__global__ __launch_bounds__(256) void pillar_scatter_fallback(
    const float* __restrict__ x, const int* __restrict__ idx,
    float* __restrict__ out)
{
    const int lane   = threadIdx.x & 15;
    const int group  = (blockIdx.x * blockDim.x + threadIdx.x) >> 4;
    const int stride = (gridDim.x * blockDim.x) >> 4;
    const float4* __restrict__ x4 = reinterpret_cast<const float4*>(x);
    for (int i = group; i < NP; i += stride) {
        const int p = idx[i];
        const float4 v = x4[i * 16 + lane];
        const int c = lane * 4;
        atomicAdd(&out[(size_t)(c + 0) * NB + p], v.x);
        atomicAdd(&out[(size_t)(c + 1) * NB + p], v.y);
        atomicAdd(&out[(size_t)(c + 2) * NB + p], v.z);
        atomicAdd(&out[(size_t)(c + 3) * NB + p], v.w);
    }
}

extern "C" void kernel_launch(void* const* d_in, const int* in_sizes, int n_in,
                              void* d_out, int out_size, void* d_ws, size_t ws_size,
                              hipStream_t stream)
{
    const float* x   = reinterpret_cast<const float*>(d_in[0]);
    const int*   idx = reinterpret_cast<const int*>(d_in[1]);
    float*       out = reinterpret_cast<float*>(d_out);

    const size_t needed = ((size_t)2 * NB + 64 + NP) * sizeof(int);
    if (ws_size < needed) {
        zero_out_kernel<<<2048, 256, 0, stream>>>(
            reinterpret_cast<float4*>(out), out_size / 4);
        pillar_scatter_fallback<<<2048, 256, 0, stream>>>(x, idx, out);
        return;
    }

    int* counts  = reinterpret_cast<int*>(d_ws);
    int* gtotal  = counts + NB;
    int* cursors = counts + NB + 64;
    int* sorted  = cursors + NB;

    const int4* idx4 = reinterpret_cast<const int4*>(idx);

    zero_kernel<<<256, 256, 0, stream>>>(
        reinterpret_cast<int4*>(counts), (NB + 64) / 4);
    hist_kernel<<<2048, 256, 0, stream>>>(idx4, counts);
    scan_kernel<<<NB / 1024, 256, 0, stream>>>(
        reinterpret_cast<const int4*>(counts), gtotal,
        reinterpret_cast<int4*>(cursors));
    scatter_kernel<<<2048, 256, 0, stream>>>(idx4, cursors, sorted);
    gather_kernel<<<NB / 64, 256, 0, stream>>>(
        reinterpret_cast<const float4*>(x), counts, cursors, sorted, out);
}

// Round 7
// 283.644 us; speedup vs baseline: 2.7284x; 1.3416x over previous
//
#include <hip/hip_runtime.h>

// PillarFeatureNet scatter-sum:
//   out[c, p] = sum_{i : indices[i]==p} x[i, c]
// x: (2,000,000, 64) fp32, indices: (2,000,000) int32 in [0, 262144)
// out: (64, 262144) fp32
//
// Round 7: rank-trick CSR build. hist's atomicAdd return value IS the
// point's rank within its pillar -> store rank[i] (coalesced 8MB), and
// scatter computes pos = base[bin] + rank[i] with NO cursor atomics.
// Atomic transactions: 6M -> 4M (R6 model: atomics ~21 G/s dominate the
// 380us; predicted -70..90us).
//
// ws layout: [counts: NB i32][gtotal+pad: 64 i32][base: NB i32]
//            [rank: NP i32][sorted: NP i32]   total ~18.1 MB

#define NP   2000000
#define NB   262144          // 512*512 pillars

__global__ __launch_bounds__(256) void zero_kernel(int4* __restrict__ p, int n4)
{
    const int stride = gridDim.x * blockDim.x;
    for (int i = blockIdx.x * blockDim.x + threadIdx.x; i < n4; i += stride)
        p[i] = make_int4(0, 0, 0, 0);
}

// Histogram; atomicAdd's old value = rank of point within its bin.
__global__ __launch_bounds__(256) void hist_rank_kernel(
    const int4* __restrict__ idx4, int* __restrict__ counts,
    int4* __restrict__ rank4)
{
    const int stride = gridDim.x * blockDim.x;
    for (int i = blockIdx.x * blockDim.x + threadIdx.x; i < NP / 4; i += stride) {
        const int4 v = idx4[i];
        int4 r;
        r.x = atomicAdd(&counts[v.x], 1);
        r.y = atomicAdd(&counts[v.y], 1);
        r.z = atomicAdd(&counts[v.z], 1);
        r.w = atomicAdd(&counts[v.w], 1);
        rank4[i] = r;
    }
}

// 256 blocks x 256 threads, 4 bins/thread. Block base via atomic ticket:
// any disjoint partition of [0,NP) is a valid CSR (order irrelevant).
__global__ __launch_bounds__(256) void scan_kernel(
    const int4* __restrict__ counts4, int* __restrict__ gtotal,
    int4* __restrict__ base4)
{
    __shared__ int lsum[256];
    __shared__ int blockBase;
    const int tid = threadIdx.x;
    const int g   = blockIdx.x * 256 + tid;

    const int4 c = counts4[g];
    const int s = c.x + c.y + c.z + c.w;
    lsum[tid] = s;
    __syncthreads();
    #pragma unroll
    for (int off = 1; off < 256; off <<= 1) {
        const int v = (tid >= off) ? lsum[tid - off] : 0;
        __syncthreads();
        lsum[tid] += v;
        __syncthreads();
    }
    const int incl = lsum[tid];
    if (tid == 255) blockBase = atomicAdd(gtotal, incl);
    __syncthreads();

    const int e = blockBase + (incl - s);
    base4[g] = make_int4(e, e + c.x, e + c.x + c.y, e + c.x + c.y + c.z);
}

// pos = base[bin] + rank  (no atomics on cursors). atomicExch write avoids
// L2 write-allocate / cross-XCD dirty-line bounce for the random 4B store.
__global__ __launch_bounds__(256) void scatter_kernel(
    const int4* __restrict__ idx4, const int4* __restrict__ rank4,
    const int* __restrict__ base, int* __restrict__ sorted)
{
    const int stride = gridDim.x * blockDim.x;
    for (int i = blockIdx.x * blockDim.x + threadIdx.x; i < NP / 4; i += stride) {
        const int4 v = idx4[i];
        const int4 r = rank4[i];
        const int p  = 4 * i;
        atomicExch(&sorted[base[v.x] + r.x], p + 0);
        atomicExch(&sorted[base[v.y] + r.y], p + 1);
        atomicExch(&sorted[base[v.z] + r.z], p + 2);
        atomicExch(&sorted[base[v.w] + r.w], p + 3);
    }
}

// One block per 64 consecutive pillars. 16 lanes per pillar (lane j owns
// channels 4j..4j+3, float4 row gathers = 256B bursts). Unroll-4 keeps 4
// dependent sorted->x chains in flight. Transpose via padded LDS tile,
// nontemporal coalesced output stores.
__global__ __launch_bounds__(256) void gather_kernel(
    const float4* __restrict__ x4,
    const int*    __restrict__ counts,
    const int*    __restrict__ base,
    const int*    __restrict__ sorted,
    float*        __restrict__ out)
{
    __shared__ float tile[64][65];
    const int p0 = blockIdx.x * 64;
    const int j  = threadIdx.x & 15;
    const int g  = threadIdx.x >> 4;

    #pragma unroll
    for (int k = 0; k < 4; ++k) {
        const int pl  = g + 16 * k;
        const int p   = p0 + pl;
        const int beg = base[p];
        const int end = beg + counts[p];
        float4 a0 = make_float4(0.f, 0.f, 0.f, 0.f);
        float4 a1 = a0, a2 = a0, a3 = a0;
        int t = beg;
        for (; t + 3 < end; t += 4) {
            const int i0 = sorted[t + 0];
            const int i1 = sorted[t + 1];
            const int i2 = sorted[t + 2];
            const int i3 = sorted[t + 3];
            const float4 v0 = x4[(size_t)i0 * 16 + j];
            const float4 v1 = x4[(size_t)i1 * 16 + j];
            const float4 v2 = x4[(size_t)i2 * 16 + j];
            const float4 v3 = x4[(size_t)i3 * 16 + j];
            a0.x += v0.x; a0.y += v0.y; a0.z += v0.z; a0.w += v0.w;
            a1.x += v1.x; a1.y += v1.y; a1.z += v1.z; a1.w += v1.w;
            a2.x += v2.x; a2.y += v2.y; a2.z += v2.z; a2.w += v2.w;
            a3.x += v3.x; a3.y += v3.y; a3.z += v3.z; a3.w += v3.w;
        }
        for (; t < end; ++t) {
            const int i0 = sorted[t];
            const float4 v0 = x4[(size_t)i0 * 16 + j];
            a0.x += v0.x; a0.y += v0.y; a0.z += v0.z; a0.w += v0.w;
        }
        tile[4 * j + 0][pl] = a0.x + a1.x + a2.x + a3.x;
        tile[4 * j + 1][pl] = a0.y + a1.y + a2.y + a3.y;
        tile[4 * j + 2][pl] = a0.z + a1.z + a2.z + a3.z;
        tile[4 * j + 3][pl] = a0.w + a1.w + a2.w + a3.w;
    }
    __syncthreads();

    const int pl = threadIdx.x & 63;
    const int cb = threadIdx.x >> 6;
    #pragma unroll
    for (int c4 = 0; c4 < 64; c4 += 4) {
        const int c = c4 + cb;
        __builtin_nontemporal_store(tile[c][pl], &out[(size_t)c * NB + p0 + pl]);
    }
}

// ---- Fallback (direct-atomic path) if workspace is too small ----
__global__ __launch_bounds__(256) void zero_out_kernel(float4* __restrict__ p, int n4)
{
    const int stride = gridDim.x * blockDim.x;
    for (int i = blockIdx.x * blockDim.x + threadIdx.x; i < n4; i += stride)
        p[i] = make_float4(0.f, 0.f, 0.f, 0.f);
}

__global__ __launch_bounds__(256) void pillar_scatter_fallback(
    const float* __restrict__ x, const int* __restrict__ idx,
    float* __restrict__ out)
{
    const int lane   = threadIdx.x & 15;
    const int group  = (blockIdx.x * blockDim.x + threadIdx.x) >> 4;
    const int stride = (gridDim.x * blockDim.x) >> 4;
    const float4* __restrict__ x4 = reinterpret_cast<const float4*>(x);
    for (int i = group; i < NP; i += stride) {
        const int p = idx[i];
        const float4 v = x4[i * 16 + lane];
        const int c = lane * 4;
        atomicAdd(&out[(size_t)(c + 0) * NB + p], v.x);
        atomicAdd(&out[(size_t)(c + 1) * NB + p], v.y);
        atomicAdd(&out[(size_t)(c + 2) * NB + p], v.z);
        atomicAdd(&out[(size_t)(c + 3) * NB + p], v.w);
    }
}

extern "C" void kernel_launch(void* const* d_in, const int* in_sizes, int n_in,
                              void* d_out, int out_size, void* d_ws, size_t ws_size,
                              hipStream_t stream)
{
    const float* x   = reinterpret_cast<const float*>(d_in[0]);
    const int*   idx = reinterpret_cast<const int*>(d_in[1]);
    float*       out = reinterpret_cast<float*>(d_out);

    const size_t needed = ((size_t)2 * NB + 64 + 2 * (size_t)NP) * sizeof(int);
    if (ws_size < needed) {
        zero_out_kernel<<<2048, 256, 0, stream>>>(
            reinterpret_cast<float4*>(out), out_size / 4);
        pillar_scatter_fallback<<<2048, 256, 0, stream>>>(x, idx, out);
        return;
    }

    int* counts = reinterpret_cast<int*>(d_ws);
    int* gtotal = counts + NB;
    int* base   = counts + NB + 64;
    int* rank   = base + NB;
    int* sorted = rank + NP;

    const int4* idx4 = reinterpret_cast<const int4*>(idx);

    zero_kernel<<<256, 256, 0, stream>>>(
        reinterpret_cast<int4*>(counts), (NB + 64) / 4);
    hist_rank_kernel<<<2048, 256, 0, stream>>>(
        idx4, counts, reinterpret_cast<int4*>(rank));
    scan_kernel<<<NB / 1024, 256, 0, stream>>>(
        reinterpret_cast<const int4*>(counts), gtotal,
        reinterpret_cast<int4*>(base));
    scatter_kernel<<<2048, 256, 0, stream>>>(
        idx4, reinterpret_cast<const int4*>(rank), base, sorted);
    gather_kernel<<<NB / 64, 256, 0, stream>>>(
        reinterpret_cast<const float4*>(x), counts, base, sorted, out);
}